// Round 3
// baseline (799.967 us; speedup 1.0000x reference)
//
#include <hip/hip_runtime.h>

#define N_NODES 8192
#define E_EDGES 524288
#define D_DIM   256
#define NEG_FILL -1e9f

#define PROJ_BLOCKS 256
#define ROWS_PER_BLOCK 32
#define FILL_BLOCKS 1792            // 256 + 1792 = 2048 blocks, one co-resident pass
#define NSLAB 256                   // 32-row slabs: 8 KB of A per slab (L1-resident)

#define PERM_BLOCKS 1024
#define EDGE_BLOCKS 2048
#define EDGES_PER_WAVE 64           // E / (EDGE_BLOCKS * 4 waves)

typedef float vfloat4 __attribute__((ext_vector_type(4)));
typedef float vfloat2 __attribute__((ext_vector_type(2)));

// K1: blocks [0,256) compute A = h@W1[0:256], B = h@W1[256:512] -> fp8 e4m3 ws
// (4 MiB total); blocks [256,2048) histogram left-endpoints into 256 slabs
// (hidden under the fill) and fill ALL of out with -1e9 via NT stores.
__global__ __launch_bounds__(256) void fill_proj_hist_kernel(
    const float* __restrict__ h,
    const float* __restrict__ W1,
    const int* __restrict__ eidx,
    float* __restrict__ out,
    unsigned char* __restrict__ AB,
    unsigned* __restrict__ hist)
{
    if (blockIdx.x < PROJ_BLOCKS) {
        __shared__ float hs[ROWS_PER_BLOCK * D_DIM];   // 32 KB
        const int t  = threadIdx.x;
        const int r0 = blockIdx.x * ROWS_PER_BLOCK;
        // h rows are read exactly once across the grid -> NT, don't pollute L2
        const vfloat4* hp4 = (const vfloat4*)(h + (long long)r0 * D_DIM);
        vfloat4* hs4 = (vfloat4*)hs;
        for (int i = t; i < ROWS_PER_BLOCK * D_DIM / 4; i += 256)
            hs4[i] = __builtin_nontemporal_load(&hp4[i]);
        __syncthreads();

        float accA[ROWS_PER_BLOCK];
        float accB[ROWS_PER_BLOCK];
        #pragma unroll
        for (int r = 0; r < ROWS_PER_BLOCK; ++r) { accA[r] = 0.f; accB[r] = 0.f; }

        for (int k = 0; k < D_DIM; k += 4) {
            float wa0 = W1[(k + 0) * D_DIM + t];
            float wa1 = W1[(k + 1) * D_DIM + t];
            float wa2 = W1[(k + 2) * D_DIM + t];
            float wa3 = W1[(k + 3) * D_DIM + t];
            float wb0 = W1[(256 + k + 0) * D_DIM + t];
            float wb1 = W1[(256 + k + 1) * D_DIM + t];
            float wb2 = W1[(256 + k + 2) * D_DIM + t];
            float wb3 = W1[(256 + k + 3) * D_DIM + t];
            #pragma unroll
            for (int r = 0; r < ROWS_PER_BLOCK; ++r) {
                const float4 hv = *(const float4*)&hs[r * D_DIM + k];
                accA[r] = fmaf(hv.x, wa0, accA[r]);
                accA[r] = fmaf(hv.y, wa1, accA[r]);
                accA[r] = fmaf(hv.z, wa2, accA[r]);
                accA[r] = fmaf(hv.w, wa3, accA[r]);
                accB[r] = fmaf(hv.x, wb0, accB[r]);
                accB[r] = fmaf(hv.y, wb1, accB[r]);
                accB[r] = fmaf(hv.z, wb2, accB[r]);
                accB[r] = fmaf(hv.w, wb3, accB[r]);
            }
        }

        unsigned char* A = AB;
        unsigned char* B = AB + (long long)N_NODES * D_DIM;
        #pragma unroll
        for (int r = 0; r < ROWS_PER_BLOCK; ++r) {
            int pa = __builtin_amdgcn_cvt_pk_fp8_f32(accA[r], accA[r], 0, false);
            int pb = __builtin_amdgcn_cvt_pk_fp8_f32(accB[r], accB[r], 0, false);
            A[(long long)(r0 + r) * D_DIM + t] = (unsigned char)(pa & 0xFF);
            B[(long long)(r0 + r) * D_DIM + t] = (unsigned char)(pb & 0xFF);
        }
    } else {
        const int b = blockIdx.x - PROJ_BLOCKS;
        // histogram (NT reads of the left-endpoint stream; atomics over 256
        // L2-resident counters, latency hidden under the fill below)
        for (int i = b * 256 + threadIdx.x; i < E_EDGES; i += FILL_BLOCKS * 256) {
            int l = __builtin_nontemporal_load(&eidx[i]);
            atomicAdd(&hist[l >> 5], 1u);
        }
        const int nvec = (N_NODES / 4) * N_NODES;   // 16777216
        vfloat4 fv = { NEG_FILL, NEG_FILL, NEG_FILL, NEG_FILL };
        vfloat4* o4 = (vfloat4*)out;
        for (int i = b * 256 + threadIdx.x; i < nvec; i += FILL_BLOCKS * 256)
            __builtin_nontemporal_store(fv, &o4[i]);
    }
}

// K1.5: exclusive prefix over the 256 slab counts -> write cursor
__global__ __launch_bounds__(NSLAB) void scan_kernel(
    const unsigned* __restrict__ hist,
    unsigned* __restrict__ cursor)
{
    __shared__ unsigned tmp[NSLAB];
    const int t = threadIdx.x;
    const unsigned v = hist[t];
    tmp[t] = v;
    __syncthreads();
    for (int off = 1; off < NSLAB; off <<= 1) {
        unsigned u = (t >= off) ? tmp[t - off] : 0u;
        __syncthreads();
        tmp[t] += u;
        __syncthreads();
    }
    cursor[t] = tmp[t] - v;     // exclusive
}

// K1.6: scatter edges into slab buckets (stable order not required).
// NT everywhere: the sorted arrays round-trip through HBM on purpose so the
// 2 MiB B-table keeps exclusive use of per-XCD L2.
__global__ __launch_bounds__(256) void permute_kernel(
    const int* __restrict__ eidx,
    const float* __restrict__ eattr,
    unsigned* __restrict__ cursor,
    unsigned* __restrict__ slr,
    float* __restrict__ sat)
{
    for (int i = blockIdx.x * 256 + threadIdx.x; i < E_EDGES; i += PERM_BLOCKS * 256) {
        const int   l = __builtin_nontemporal_load(&eidx[i]);
        const int   r = __builtin_nontemporal_load(&eidx[E_EDGES + i]);
        const float a = __builtin_nontemporal_load(&eattr[i]);
        const unsigned pos = atomicAdd(&cursor[l >> 5], 1u);
        __builtin_nontemporal_store(((unsigned)l << 16) | (unsigned)r, &slr[pos]);
        __builtin_nontemporal_store(a, &sat[pos]);
    }
}

// K2: 2048 blocks x 4 waves; each wave owns 64 consecutive SORTED edges
// (slab-local left rows -> A-gathers hit L1; B-gathers hit the now-resident
// 2 MiB L2 table; out-scatter is row-local). 16 lanes per edge, 4 edges per
// wave-iteration; 1-deep pipeline on the two 256 B fp8 row-gathers.
__global__ __launch_bounds__(256) void edge_kernel(
    const unsigned* __restrict__ slr,
    const float* __restrict__ sat,
    const float* __restrict__ W1,
    const float* __restrict__ W2,
    const unsigned char* __restrict__ AB,
    float* __restrict__ out)
{
    // XCD-aware swizzle (2048 % 8 == 0 -> bijective): contiguous slab runs
    // stay on one XCD so its L2/L1 see a small hot A working set.
    const int bid  = (blockIdx.x & 7) * (EDGE_BLOCKS / 8) + (blockIdx.x >> 3);
    const int wave = bid * 4 + (threadIdx.x >> 6);
    const int lane = threadIdx.x & 63;
    const int g    = lane >> 4;          // group 0..3 (one edge each per iter)
    const int t    = lane & 15;          // lane-in-group: dims [t*16, t*16+16)
    const int ebase = wave * EDGES_PER_WAVE;

    // this wave's 64 edges, one per lane (2 coalesced NT loads)
    const unsigned lr_all = __builtin_nontemporal_load(&slr[ebase + lane]);
    const float    a_all  = __builtin_nontemporal_load(&sat[ebase + lane]);

    const int j0 = t * 16;
    const float4 wl0 = *(const float4*)&W1[512 * D_DIM + j0 + 0];
    const float4 wl1 = *(const float4*)&W1[512 * D_DIM + j0 + 4];
    const float4 wl2 = *(const float4*)&W1[512 * D_DIM + j0 + 8];
    const float4 wl3 = *(const float4*)&W1[512 * D_DIM + j0 + 12];
    const float4 w20 = *(const float4*)&W2[j0 + 0];
    const float4 w21 = *(const float4*)&W2[j0 + 4];
    const float4 w22 = *(const float4*)&W2[j0 + 8];
    const float4 w23 = *(const float4*)&W2[j0 + 12];
    const unsigned char* Bt = AB + (long long)N_NODES * D_DIM;

    // prime the pipeline with edges 0..3 (one per group)
    unsigned lr_c = (unsigned)__shfl((int)lr_all, g);
    float    at_c = __shfl(a_all, g);
    int l_c = (int)(lr_c >> 16), r_c = (int)(lr_c & 0xFFFFu);
    uint4 av_c = *(const uint4*)(AB + (unsigned)l_c * D_DIM + j0);
    uint4 bv_c = *(const uint4*)(Bt + (unsigned)r_c * D_DIM + j0);

    #pragma unroll 4
    for (int i = 0; i < EDGES_PER_WAVE / 4; ++i) {
        const int   l_cur = l_c;
        const int   r_cur = r_c;
        const float attr  = at_c;
        const uint4 av    = av_c;
        const uint4 bv    = bv_c;
        if (i + 1 < EDGES_PER_WAVE / 4) {    // issue next gathers before compute
            unsigned lr_n = (unsigned)__shfl((int)lr_all, 4 * (i + 1) + g);
            at_c = __shfl(a_all, 4 * (i + 1) + g);
            l_c = (int)(lr_n >> 16); r_c = (int)(lr_n & 0xFFFFu);
            av_c = *(const uint4*)(AB + (unsigned)l_c * D_DIM + j0);
            bv_c = *(const uint4*)(Bt + (unsigned)r_c * D_DIM + j0);
        }

        float s = 0.f;
        #define MLP_STEP(AV, BV, WL, W2V) {                                        \
            vfloat2 alo = __builtin_amdgcn_cvt_pk_f32_fp8((int)(AV), false);       \
            vfloat2 ahi = __builtin_amdgcn_cvt_pk_f32_fp8((int)(AV), true);        \
            vfloat2 blo = __builtin_amdgcn_cvt_pk_f32_fp8((int)(BV), false);       \
            vfloat2 bhi = __builtin_amdgcn_cvt_pk_f32_fp8((int)(BV), true);        \
            float hv;                                                              \
            hv = fmaf(attr, WL.x, alo.x + blo.x); hv = fmaxf(hv, 0.f); s = fmaf(hv, W2V.x, s); \
            hv = fmaf(attr, WL.y, alo.y + blo.y); hv = fmaxf(hv, 0.f); s = fmaf(hv, W2V.y, s); \
            hv = fmaf(attr, WL.z, ahi.x + bhi.x); hv = fmaxf(hv, 0.f); s = fmaf(hv, W2V.z, s); \
            hv = fmaf(attr, WL.w, ahi.y + bhi.y); hv = fmaxf(hv, 0.f); s = fmaf(hv, W2V.w, s); \
        }
        MLP_STEP(av.x, bv.x, wl0, w20);
        MLP_STEP(av.y, bv.y, wl1, w21);
        MLP_STEP(av.z, bv.z, wl2, w22);
        MLP_STEP(av.w, bv.w, wl3, w23);
        #undef MLP_STEP

        // reduce the 16-lane partial sums within each group
        s += __shfl_xor(s, 8);
        s += __shfl_xor(s, 4);
        s += __shfl_xor(s, 2);
        s += __shfl_xor(s, 1);

        if (t == 0)
            __builtin_nontemporal_store(
                s, &out[(long long)l_cur * N_NODES + r_cur]);
    }
}

extern "C" void kernel_launch(void* const* d_in, const int* in_sizes, int n_in,
                              void* d_out, int out_size, void* d_ws, size_t ws_size,
                              hipStream_t stream) {
    // inputs: 0=encoded (unused), 1=h, 2=edge_index, 3=edge_attr, 4=W1, 5=W2
    const float* h     = (const float*)d_in[1];
    const int*   eidx  = (const int*)d_in[2];
    const float* eattr = (const float*)d_in[3];
    const float* W1    = (const float*)d_in[4];
    const float* W2    = (const float*)d_in[5];
    float* out = (float*)d_out;

    // ws layout: [0,4M) AB fp8 tables; [4M,6M) sorted lr; [6M,8M) sorted attr;
    //            [8M, +1K) hist; [8M+1K, +1K) cursor
    unsigned char* AB     = (unsigned char*)d_ws;
    unsigned*      slr    = (unsigned*)((char*)d_ws + (4u << 20));
    float*         sat    = (float*)((char*)d_ws + (6u << 20));
    unsigned*      hist   = (unsigned*)((char*)d_ws + (8u << 20));
    unsigned*      cursor = hist + NSLAB;

    (void)hipMemsetAsync(hist, 0, NSLAB * sizeof(unsigned), stream);
    fill_proj_hist_kernel<<<PROJ_BLOCKS + FILL_BLOCKS, 256, 0, stream>>>(h, W1, eidx, out, AB, hist);
    scan_kernel<<<1, NSLAB, 0, stream>>>(hist, cursor);
    permute_kernel<<<PERM_BLOCKS, 256, 0, stream>>>(eidx, eattr, cursor, slr, sat);
    edge_kernel<<<EDGE_BLOCKS, 256, 0, stream>>>(slr, sat, W1, W2, AB, out);
}

// Round 4
// 449.481 us; speedup vs baseline: 1.7798x; 1.7798x over previous
//
#include <hip/hip_runtime.h>

#define N_NODES 8192
#define E_EDGES 524288
#define D_DIM   256
#define NEG_FILL -1e9f

#define PROJ_BLOCKS 256
#define ROWS_PER_BLOCK 32
#define FILL_BLOCKS 1792            // 256 + 1792 = 2048 blocks, one co-resident pass
#define NSLAB 256                   // 32-row slabs: 8 KB of A per slab (L1-resident)
#define CPAD 32                     // counter padding: 1 counter per 128 B line

#define PERM_BLOCKS 1024
#define EDGE_BLOCKS 2048
#define EDGES_PER_WAVE 64           // E / (EDGE_BLOCKS * 4 waves)

typedef float vfloat4 __attribute__((ext_vector_type(4)));
typedef float vfloat2 __attribute__((ext_vector_type(2)));

// K1: blocks [0,256) compute A = h@W1[0:256], B = h@W1[256:512] -> fp8 e4m3 ws
// (4 MiB total); blocks [256,2048) histogram left-endpoints into 256 slab
// counters (one per 128 B line -> no atomic line contention; hidden under the
// fill) and fill ALL of out with -1e9 via NT stores.
__global__ __launch_bounds__(256) void fill_proj_hist_kernel(
    const float* __restrict__ h,
    const float* __restrict__ W1,
    const int* __restrict__ eidx,
    float* __restrict__ out,
    unsigned char* __restrict__ AB,
    unsigned* __restrict__ hist)
{
    if (blockIdx.x < PROJ_BLOCKS) {
        __shared__ float hs[ROWS_PER_BLOCK * D_DIM];   // 32 KB
        const int t  = threadIdx.x;
        const int r0 = blockIdx.x * ROWS_PER_BLOCK;
        // h rows are read exactly once across the grid -> NT, don't pollute L2
        const vfloat4* hp4 = (const vfloat4*)(h + (long long)r0 * D_DIM);
        vfloat4* hs4 = (vfloat4*)hs;
        for (int i = t; i < ROWS_PER_BLOCK * D_DIM / 4; i += 256)
            hs4[i] = __builtin_nontemporal_load(&hp4[i]);
        __syncthreads();

        float accA[ROWS_PER_BLOCK];
        float accB[ROWS_PER_BLOCK];
        #pragma unroll
        for (int r = 0; r < ROWS_PER_BLOCK; ++r) { accA[r] = 0.f; accB[r] = 0.f; }

        for (int k = 0; k < D_DIM; k += 4) {
            float wa0 = W1[(k + 0) * D_DIM + t];
            float wa1 = W1[(k + 1) * D_DIM + t];
            float wa2 = W1[(k + 2) * D_DIM + t];
            float wa3 = W1[(k + 3) * D_DIM + t];
            float wb0 = W1[(256 + k + 0) * D_DIM + t];
            float wb1 = W1[(256 + k + 1) * D_DIM + t];
            float wb2 = W1[(256 + k + 2) * D_DIM + t];
            float wb3 = W1[(256 + k + 3) * D_DIM + t];
            #pragma unroll
            for (int r = 0; r < ROWS_PER_BLOCK; ++r) {
                const float4 hv = *(const float4*)&hs[r * D_DIM + k];
                accA[r] = fmaf(hv.x, wa0, accA[r]);
                accA[r] = fmaf(hv.y, wa1, accA[r]);
                accA[r] = fmaf(hv.z, wa2, accA[r]);
                accA[r] = fmaf(hv.w, wa3, accA[r]);
                accB[r] = fmaf(hv.x, wb0, accB[r]);
                accB[r] = fmaf(hv.y, wb1, accB[r]);
                accB[r] = fmaf(hv.z, wb2, accB[r]);
                accB[r] = fmaf(hv.w, wb3, accB[r]);
            }
        }

        unsigned char* A = AB;
        unsigned char* B = AB + (long long)N_NODES * D_DIM;
        #pragma unroll
        for (int r = 0; r < ROWS_PER_BLOCK; ++r) {
            int pa = __builtin_amdgcn_cvt_pk_fp8_f32(accA[r], accA[r], 0, false);
            int pb = __builtin_amdgcn_cvt_pk_fp8_f32(accB[r], accB[r], 0, false);
            A[(long long)(r0 + r) * D_DIM + t] = (unsigned char)(pa & 0xFF);
            B[(long long)(r0 + r) * D_DIM + t] = (unsigned char)(pb & 0xFF);
        }
    } else {
        const int b = blockIdx.x - PROJ_BLOCKS;
        // histogram: counters padded to 1/line -> ~2048 ops per line, spread
        // across 256 lines; latency hidden under the fill below
        for (int i = b * 256 + threadIdx.x; i < E_EDGES; i += FILL_BLOCKS * 256) {
            int l = __builtin_nontemporal_load(&eidx[i]);
            atomicAdd(&hist[(unsigned)(l >> 5) * CPAD], 1u);
        }
        const int nvec = (N_NODES / 4) * N_NODES;   // 16777216
        vfloat4 fv = { NEG_FILL, NEG_FILL, NEG_FILL, NEG_FILL };
        vfloat4* o4 = (vfloat4*)out;
        for (int i = b * 256 + threadIdx.x; i < nvec; i += FILL_BLOCKS * 256)
            __builtin_nontemporal_store(fv, &o4[i]);
    }
}

// K1.5: exclusive prefix over the 256 (padded) slab counts -> write cursor
__global__ __launch_bounds__(NSLAB) void scan_kernel(
    const unsigned* __restrict__ hist,
    unsigned* __restrict__ cursor)
{
    __shared__ unsigned tmp[NSLAB];
    const int t = threadIdx.x;
    const unsigned v = hist[t * CPAD];
    tmp[t] = v;
    __syncthreads();
    for (int off = 1; off < NSLAB; off <<= 1) {
        unsigned u = (t >= off) ? tmp[t - off] : 0u;
        __syncthreads();
        tmp[t] += u;
        __syncthreads();
    }
    cursor[t * CPAD] = tmp[t] - v;     // exclusive
}

// K1.6: scatter edges into slab buckets (stable order not required).
// Cursor counters padded 1/line -> atomic RMWs parallel across lines.
// NT data path: sorted arrays round-trip HBM on purpose so the 2 MiB B-table
// keeps per-XCD L2 to itself.
__global__ __launch_bounds__(256) void permute_kernel(
    const int* __restrict__ eidx,
    const float* __restrict__ eattr,
    unsigned* __restrict__ cursor,
    unsigned* __restrict__ slr,
    float* __restrict__ sat)
{
    for (int i = blockIdx.x * 256 + threadIdx.x; i < E_EDGES; i += PERM_BLOCKS * 256) {
        const int   l = __builtin_nontemporal_load(&eidx[i]);
        const int   r = __builtin_nontemporal_load(&eidx[E_EDGES + i]);
        const float a = __builtin_nontemporal_load(&eattr[i]);
        const unsigned pos = atomicAdd(&cursor[(unsigned)(l >> 5) * CPAD], 1u);
        __builtin_nontemporal_store(((unsigned)l << 16) | (unsigned)r, &slr[pos]);
        __builtin_nontemporal_store(a, &sat[pos]);
    }
}

// K2: 2048 blocks x 4 waves; each wave owns 64 consecutive SORTED edges
// (slab-local left rows -> A-gathers hit L1; B-gathers hit the now-resident
// 2 MiB L2 table; out-scatter is row-local). 16 lanes per edge, 4 edges per
// wave-iteration; 1-deep pipeline on the two 256 B fp8 row-gathers.
__global__ __launch_bounds__(256) void edge_kernel(
    const unsigned* __restrict__ slr,
    const float* __restrict__ sat,
    const float* __restrict__ W1,
    const float* __restrict__ W2,
    const unsigned char* __restrict__ AB,
    float* __restrict__ out)
{
    // XCD-aware swizzle (2048 % 8 == 0 -> bijective): contiguous slab runs
    // stay on one XCD so its L2/L1 see a small hot A working set.
    const int bid  = (blockIdx.x & 7) * (EDGE_BLOCKS / 8) + (blockIdx.x >> 3);
    const int wave = bid * 4 + (threadIdx.x >> 6);
    const int lane = threadIdx.x & 63;
    const int g    = lane >> 4;          // group 0..3 (one edge each per iter)
    const int t    = lane & 15;          // lane-in-group: dims [t*16, t*16+16)
    const int ebase = wave * EDGES_PER_WAVE;

    // this wave's 64 edges, one per lane (2 coalesced NT loads)
    const unsigned lr_all = __builtin_nontemporal_load(&slr[ebase + lane]);
    const float    a_all  = __builtin_nontemporal_load(&sat[ebase + lane]);

    const int j0 = t * 16;
    const float4 wl0 = *(const float4*)&W1[512 * D_DIM + j0 + 0];
    const float4 wl1 = *(const float4*)&W1[512 * D_DIM + j0 + 4];
    const float4 wl2 = *(const float4*)&W1[512 * D_DIM + j0 + 8];
    const float4 wl3 = *(const float4*)&W1[512 * D_DIM + j0 + 12];
    const float4 w20 = *(const float4*)&W2[j0 + 0];
    const float4 w21 = *(const float4*)&W2[j0 + 4];
    const float4 w22 = *(const float4*)&W2[j0 + 8];
    const float4 w23 = *(const float4*)&W2[j0 + 12];
    const unsigned char* Bt = AB + (long long)N_NODES * D_DIM;

    // prime the pipeline with edges 0..3 (one per group)
    unsigned lr_c = (unsigned)__shfl((int)lr_all, g);
    float    at_c = __shfl(a_all, g);
    int l_c = (int)(lr_c >> 16), r_c = (int)(lr_c & 0xFFFFu);
    uint4 av_c = *(const uint4*)(AB + (unsigned)l_c * D_DIM + j0);
    uint4 bv_c = *(const uint4*)(Bt + (unsigned)r_c * D_DIM + j0);

    #pragma unroll 4
    for (int i = 0; i < EDGES_PER_WAVE / 4; ++i) {
        const int   l_cur = l_c;
        const int   r_cur = r_c;
        const float attr  = at_c;
        const uint4 av    = av_c;
        const uint4 bv    = bv_c;
        if (i + 1 < EDGES_PER_WAVE / 4) {    // issue next gathers before compute
            unsigned lr_n = (unsigned)__shfl((int)lr_all, 4 * (i + 1) + g);
            at_c = __shfl(a_all, 4 * (i + 1) + g);
            l_c = (int)(lr_n >> 16); r_c = (int)(lr_n & 0xFFFFu);
            av_c = *(const uint4*)(AB + (unsigned)l_c * D_DIM + j0);
            bv_c = *(const uint4*)(Bt + (unsigned)r_c * D_DIM + j0);
        }

        float s = 0.f;
        #define MLP_STEP(AV, BV, WL, W2V) {                                        \
            vfloat2 alo = __builtin_amdgcn_cvt_pk_f32_fp8((int)(AV), false);       \
            vfloat2 ahi = __builtin_amdgcn_cvt_pk_f32_fp8((int)(AV), true);        \
            vfloat2 blo = __builtin_amdgcn_cvt_pk_f32_fp8((int)(BV), false);       \
            vfloat2 bhi = __builtin_amdgcn_cvt_pk_f32_fp8((int)(BV), true);        \
            float hv;                                                              \
            hv = fmaf(attr, WL.x, alo.x + blo.x); hv = fmaxf(hv, 0.f); s = fmaf(hv, W2V.x, s); \
            hv = fmaf(attr, WL.y, alo.y + blo.y); hv = fmaxf(hv, 0.f); s = fmaf(hv, W2V.y, s); \
            hv = fmaf(attr, WL.z, ahi.x + bhi.x); hv = fmaxf(hv, 0.f); s = fmaf(hv, W2V.z, s); \
            hv = fmaf(attr, WL.w, ahi.y + bhi.y); hv = fmaxf(hv, 0.f); s = fmaf(hv, W2V.w, s); \
        }
        MLP_STEP(av.x, bv.x, wl0, w20);
        MLP_STEP(av.y, bv.y, wl1, w21);
        MLP_STEP(av.z, bv.z, wl2, w22);
        MLP_STEP(av.w, bv.w, wl3, w23);
        #undef MLP_STEP

        // reduce the 16-lane partial sums within each group
        s += __shfl_xor(s, 8);
        s += __shfl_xor(s, 4);
        s += __shfl_xor(s, 2);
        s += __shfl_xor(s, 1);

        if (t == 0)
            __builtin_nontemporal_store(
                s, &out[(long long)l_cur * N_NODES + r_cur]);
    }
}

extern "C" void kernel_launch(void* const* d_in, const int* in_sizes, int n_in,
                              void* d_out, int out_size, void* d_ws, size_t ws_size,
                              hipStream_t stream) {
    // inputs: 0=encoded (unused), 1=h, 2=edge_index, 3=edge_attr, 4=W1, 5=W2
    const float* h     = (const float*)d_in[1];
    const int*   eidx  = (const int*)d_in[2];
    const float* eattr = (const float*)d_in[3];
    const float* W1    = (const float*)d_in[4];
    const float* W2    = (const float*)d_in[5];
    float* out = (float*)d_out;

    // ws layout: [0,4M) AB fp8 tables; [4M,6M) sorted lr; [6M,8M) sorted attr;
    //            [8M, +32K) hist (padded 1/128B); [8M+32K, +32K) cursor
    unsigned char* AB     = (unsigned char*)d_ws;
    unsigned*      slr    = (unsigned*)((char*)d_ws + (4u << 20));
    float*         sat    = (float*)((char*)d_ws + (6u << 20));
    unsigned*      hist   = (unsigned*)((char*)d_ws + (8u << 20));
    unsigned*      cursor = hist + NSLAB * CPAD;

    (void)hipMemsetAsync(hist, 0, NSLAB * CPAD * sizeof(unsigned), stream);
    fill_proj_hist_kernel<<<PROJ_BLOCKS + FILL_BLOCKS, 256, 0, stream>>>(h, W1, eidx, out, AB, hist);
    scan_kernel<<<1, NSLAB, 0, stream>>>(hist, cursor);
    permute_kernel<<<PERM_BLOCKS, 256, 0, stream>>>(eidx, eattr, cursor, slr, sat);
    edge_kernel<<<EDGE_BLOCKS, 256, 0, stream>>>(slr, sat, W1, W2, AB, out);
}

// Round 5
// 382.923 us; speedup vs baseline: 2.0891x; 1.1738x over previous
//
#include <hip/hip_runtime.h>

#define N_NODES 8192
#define E_EDGES 524288
#define D_DIM   256
#define NEG_FILL -1e9f

#define PROJ_BLOCKS 256
#define ROWS_PER_BLOCK 32
#define FILL_BLOCKS 1792            // 256 + 1792 = 2048 blocks, one co-resident pass

#define EDGE_BLOCKS 2048
#define EDGES_PER_WAVE 64           // E / (EDGE_BLOCKS * 4 waves)
#define DEPTH 4                     // K2 software-pipeline depth (edge-groups in flight)

typedef float vfloat4 __attribute__((ext_vector_type(4)));
typedef float vfloat2 __attribute__((ext_vector_type(2)));

// K1: blocks [0,256) compute A = h@W1[0:256], B = h@W1[256:512] -> fp8 e4m3 ws
// (4 MiB total, L2-resident for K2's gathers); blocks [256,2048) fill ALL of
// out with -1e9 via NT stores. Proj is VALU-bound and hides under the fill.
__global__ __launch_bounds__(256) void fill_proj_kernel(
    const float* __restrict__ h,
    const float* __restrict__ W1,
    float* __restrict__ out,
    unsigned char* __restrict__ AB)
{
    if (blockIdx.x < PROJ_BLOCKS) {
        __shared__ float hs[ROWS_PER_BLOCK * D_DIM];   // 32 KB
        const int t  = threadIdx.x;
        const int r0 = blockIdx.x * ROWS_PER_BLOCK;
        // h rows are read exactly once across the grid -> NT, don't pollute L2
        const vfloat4* hp4 = (const vfloat4*)(h + (long long)r0 * D_DIM);
        vfloat4* hs4 = (vfloat4*)hs;
        for (int i = t; i < ROWS_PER_BLOCK * D_DIM / 4; i += 256)
            hs4[i] = __builtin_nontemporal_load(&hp4[i]);
        __syncthreads();

        float accA[ROWS_PER_BLOCK];
        float accB[ROWS_PER_BLOCK];
        #pragma unroll
        for (int r = 0; r < ROWS_PER_BLOCK; ++r) { accA[r] = 0.f; accB[r] = 0.f; }

        for (int k = 0; k < D_DIM; k += 4) {
            float wa0 = W1[(k + 0) * D_DIM + t];
            float wa1 = W1[(k + 1) * D_DIM + t];
            float wa2 = W1[(k + 2) * D_DIM + t];
            float wa3 = W1[(k + 3) * D_DIM + t];
            float wb0 = W1[(256 + k + 0) * D_DIM + t];
            float wb1 = W1[(256 + k + 1) * D_DIM + t];
            float wb2 = W1[(256 + k + 2) * D_DIM + t];
            float wb3 = W1[(256 + k + 3) * D_DIM + t];
            #pragma unroll
            for (int r = 0; r < ROWS_PER_BLOCK; ++r) {
                const float4 hv = *(const float4*)&hs[r * D_DIM + k];
                accA[r] = fmaf(hv.x, wa0, accA[r]);
                accA[r] = fmaf(hv.y, wa1, accA[r]);
                accA[r] = fmaf(hv.z, wa2, accA[r]);
                accA[r] = fmaf(hv.w, wa3, accA[r]);
                accB[r] = fmaf(hv.x, wb0, accB[r]);
                accB[r] = fmaf(hv.y, wb1, accB[r]);
                accB[r] = fmaf(hv.z, wb2, accB[r]);
                accB[r] = fmaf(hv.w, wb3, accB[r]);
            }
        }

        unsigned char* A = AB;
        unsigned char* B = AB + (long long)N_NODES * D_DIM;
        #pragma unroll
        for (int r = 0; r < ROWS_PER_BLOCK; ++r) {
            int pa = __builtin_amdgcn_cvt_pk_fp8_f32(accA[r], accA[r], 0, false);
            int pb = __builtin_amdgcn_cvt_pk_fp8_f32(accB[r], accB[r], 0, false);
            A[(long long)(r0 + r) * D_DIM + t] = (unsigned char)(pa & 0xFF);
            B[(long long)(r0 + r) * D_DIM + t] = (unsigned char)(pb & 0xFF);
        }
    } else {
        const int b = blockIdx.x - PROJ_BLOCKS;
        const int nvec = (N_NODES / 4) * N_NODES;   // 16777216
        vfloat4 fv = { NEG_FILL, NEG_FILL, NEG_FILL, NEG_FILL };
        vfloat4* o4 = (vfloat4*)out;
        for (int i = b * 256 + threadIdx.x; i < nvec; i += FILL_BLOCKS * 256)
            __builtin_nontemporal_store(fv, &o4[i]);
    }
}

// K2: 2048 blocks x 4 waves; each wave owns 64 consecutive edges.
// 16 lanes per edge, 4 edges per wave-iteration (16 iterations), and a
// DEPTH=4 ring of prefetched edge-groups: 8 gathers in flight per wave to
// hide HBM-miss latency (~900 cy) that a 1-deep pipeline couldn't cover.
// Loop is fully unrolled so all ring indices are compile-time (no scratch).
__global__ __launch_bounds__(256) void edge_kernel(
    const int* __restrict__ eidx,
    const float* __restrict__ eattr,
    const float* __restrict__ W1,
    const float* __restrict__ W2,
    const unsigned char* __restrict__ AB,
    float* __restrict__ out)
{
    const int wave = blockIdx.x * 4 + (threadIdx.x >> 6);
    const int lane = threadIdx.x & 63;
    const int g    = lane >> 4;          // group 0..3 (one edge each per iter)
    const int t    = lane & 15;          // lane-in-group: dims [t*16, t*16+16)
    const int base = wave * EDGES_PER_WAVE;

    // this wave's 64 edges, one per lane (3 coalesced NT loads — streams
    // read once; keep them out of L2 so the AB table stays resident)
    const int   l_all = __builtin_nontemporal_load(&eidx[base + lane]);
    const int   r_all = __builtin_nontemporal_load(&eidx[E_EDGES + base + lane]);
    const float a_all = __builtin_nontemporal_load(&eattr[base + lane]);

    const int j0 = t * 16;
    const float4 wl0 = *(const float4*)&W1[512 * D_DIM + j0 + 0];
    const float4 wl1 = *(const float4*)&W1[512 * D_DIM + j0 + 4];
    const float4 wl2 = *(const float4*)&W1[512 * D_DIM + j0 + 8];
    const float4 wl3 = *(const float4*)&W1[512 * D_DIM + j0 + 12];
    const float4 w20 = *(const float4*)&W2[j0 + 0];
    const float4 w21 = *(const float4*)&W2[j0 + 4];
    const float4 w22 = *(const float4*)&W2[j0 + 8];
    const float4 w23 = *(const float4*)&W2[j0 + 12];
    const unsigned char* Bt = AB + (long long)N_NODES * D_DIM;

    // prime the ring with edge-groups 0..DEPTH-1
    int   ls[DEPTH], rs[DEPTH];
    float ats[DEPTH];
    uint4 avs[DEPTH], bvs[DEPTH];
    #pragma unroll
    for (int p = 0; p < DEPTH; ++p) {
        ls[p]  = __shfl(l_all, 4 * p + g);
        rs[p]  = __shfl(r_all, 4 * p + g);
        ats[p] = __shfl(a_all, 4 * p + g);
        avs[p] = *(const uint4*)(AB + (unsigned)ls[p] * D_DIM + j0);
        bvs[p] = *(const uint4*)(Bt + (unsigned)rs[p] * D_DIM + j0);
    }

    #pragma unroll
    for (int i = 0; i < EDGES_PER_WAVE / 4; ++i) {
        const int s = i & (DEPTH - 1);           // compile-time (full unroll)
        const int   l_cur = ls[s];
        const int   r_cur = rs[s];
        const float attr  = ats[s];
        const uint4 av    = avs[s];
        const uint4 bv    = bvs[s];
        if (i + DEPTH < EDGES_PER_WAVE / 4) {    // refill this ring slot
            ls[s]  = __shfl(l_all, 4 * (i + DEPTH) + g);
            rs[s]  = __shfl(r_all, 4 * (i + DEPTH) + g);
            ats[s] = __shfl(a_all, 4 * (i + DEPTH) + g);
            avs[s] = *(const uint4*)(AB + (unsigned)ls[s] * D_DIM + j0);
            bvs[s] = *(const uint4*)(Bt + (unsigned)rs[s] * D_DIM + j0);
        }

        float sacc = 0.f;
        #define MLP_STEP(AV, BV, WL, W2V) {                                        \
            vfloat2 alo = __builtin_amdgcn_cvt_pk_f32_fp8((int)(AV), false);       \
            vfloat2 ahi = __builtin_amdgcn_cvt_pk_f32_fp8((int)(AV), true);        \
            vfloat2 blo = __builtin_amdgcn_cvt_pk_f32_fp8((int)(BV), false);       \
            vfloat2 bhi = __builtin_amdgcn_cvt_pk_f32_fp8((int)(BV), true);        \
            float hv;                                                              \
            hv = fmaf(attr, WL.x, alo.x + blo.x); hv = fmaxf(hv, 0.f); sacc = fmaf(hv, W2V.x, sacc); \
            hv = fmaf(attr, WL.y, alo.y + blo.y); hv = fmaxf(hv, 0.f); sacc = fmaf(hv, W2V.y, sacc); \
            hv = fmaf(attr, WL.z, ahi.x + bhi.x); hv = fmaxf(hv, 0.f); sacc = fmaf(hv, W2V.z, sacc); \
            hv = fmaf(attr, WL.w, ahi.y + bhi.y); hv = fmaxf(hv, 0.f); sacc = fmaf(hv, W2V.w, sacc); \
        }
        MLP_STEP(av.x, bv.x, wl0, w20);
        MLP_STEP(av.y, bv.y, wl1, w21);
        MLP_STEP(av.z, bv.z, wl2, w22);
        MLP_STEP(av.w, bv.w, wl3, w23);
        #undef MLP_STEP

        // reduce the 16-lane partial sums within each group
        sacc += __shfl_xor(sacc, 8);
        sacc += __shfl_xor(sacc, 4);
        sacc += __shfl_xor(sacc, 2);
        sacc += __shfl_xor(sacc, 1);

        if (t == 0)
            __builtin_nontemporal_store(
                sacc, &out[(long long)l_cur * N_NODES + r_cur]);
    }
}

extern "C" void kernel_launch(void* const* d_in, const int* in_sizes, int n_in,
                              void* d_out, int out_size, void* d_ws, size_t ws_size,
                              hipStream_t stream) {
    // inputs: 0=encoded (unused), 1=h, 2=edge_index, 3=edge_attr, 4=W1, 5=W2
    const float* h     = (const float*)d_in[1];
    const int*   eidx  = (const int*)d_in[2];
    const float* eattr = (const float*)d_in[3];
    const float* W1    = (const float*)d_in[4];
    const float* W2    = (const float*)d_in[5];
    float* out = (float*)d_out;
    unsigned char* AB = (unsigned char*)d_ws;   // 4 MiB (2 * N * D fp8)

    fill_proj_kernel<<<PROJ_BLOCKS + FILL_BLOCKS, 256, 0, stream>>>(h, W1, out, AB);
    edge_kernel<<<EDGE_BLOCKS, 256, 0, stream>>>(eidx, eattr, W1, W2, AB, out);
}